// Round 7
// baseline (604.728 us; speedup 1.0000x reference)
//
#include <hip/hip_runtime.h>

typedef _Float16 f16;
typedef __attribute__((ext_vector_type(8))) _Float16 f16x8;
typedef __attribute__((ext_vector_type(4))) _Float16 f16x4;
typedef __attribute__((ext_vector_type(4))) float    f32x4;

#define MFMA(a,b,c) __builtin_amdgcn_mfma_f32_16x16x32_f16(a,b,c,0,0,0)

// problem constants
constexpr int Bc = 2, Nc = 65536, Cc = 256, Hc = 8;
constexpr int CHUNK = 512;                 // tokens per block: 4 m0-tiles of 128
constexpr int LDX = 72;                    // X staging stride (144B rows — 16B ALIGNED; r2/r3: misalign = 2.3x)
constexpr int LDT = 136;                   // transpose stride (272B rows)
constexpr int LDW = 64;                    // W DMA tile stride (linear, both-sides swizzled)

// ---- workspace layout (bytes) ----
// 0      : Tg    float[16*4096] (262144)
// 262144 : normg float[16*64]   (4096)
// 266240 : WC    f16[8*128*256] (524288)  [h][n][k]; n 0..63 = Wfx cols, 64..127 = Wxs
// 790528 : bsp   float[8*64]    (2048)

__device__ __forceinline__ f32x4 splat4(float v) { f32x4 r; r.x=v; r.y=v; r.z=v; r.w=v; return r; }
__device__ __forceinline__ f16x8 pack8(float4 a, float4 b) {
  f16x8 r = { (f16)a.x,(f16)a.y,(f16)a.z,(f16)a.w,(f16)b.x,(f16)b.y,(f16)b.z,(f16)b.w };
  return r;
}
__device__ __forceinline__ void gl_lds16(const f16* g, f16* l) {
  __builtin_amdgcn_global_load_lds((const __attribute__((address_space(1))) void*)g,
                                   (__attribute__((address_space(3))) void*)l, 16, 0, 0);
}
// barrier draining only LDS ops (frag reads / ds_writes); rule-18 fences.
__device__ __forceinline__ void bar_lgkm() {
  __builtin_amdgcn_sched_barrier(0);
  asm volatile("s_waitcnt lgkmcnt(0)" ::: "memory");
  __builtin_amdgcn_s_barrier();
  __builtin_amdgcn_sched_barrier(0);
}
// counted-vm barrier: N VMEM ops may stay in flight (the 8 xr prefetch loads);
// the 4 older W-DMA ops must have retired (FIFO) -> W tile landed. lgkm(0)
// makes this step's ds_writes visible across the barrier.
template<int N> __device__ __forceinline__ void bar_vmN() {
  __builtin_amdgcn_sched_barrier(0);
  if (N == 0) asm volatile("s_waitcnt vmcnt(0) lgkmcnt(0)" ::: "memory");
  else        asm volatile("s_waitcnt vmcnt(8) lgkmcnt(0)" ::: "memory");
  __builtin_amdgcn_s_barrier();
  __builtin_amdgcn_sched_barrier(0);
}

// prep: 162 blocks. b<32: Wfx transpose; 32<=b<96: Wxs; b==96: bsp;
// 97<=b<162: zero Tg+normg.
__global__ void prep_a(const float* __restrict__ Wx, const float* __restrict__ Wfx,
                       const float* __restrict__ Wsl, const float* __restrict__ bx,
                       const float* __restrict__ bsl, f16* __restrict__ WC,
                       float* __restrict__ bsp, float* __restrict__ Tz) {
  __shared__ float tile[64][72];
  const int b = blockIdx.x, t = threadIdx.x;
  if (b < 32) {
    const int k0 = (b & 3) * 64, c0 = (b >> 2) * 64;
    const int r = t >> 4, c4 = (t & 15) * 4;
    #pragma unroll
    for (int i = 0; i < 4; ++i) {
      float4 v = *(const float4*)&Wfx[(size_t)(k0 + r + i*16)*512 + c0 + c4];
      tile[r + i*16][c4] = v.x; tile[r + i*16][c4+1] = v.y;
      tile[r + i*16][c4+2] = v.z; tile[r + i*16][c4+3] = v.w;
    }
    __syncthreads();
    const int cl = t >> 2, kq = t & 3;
    const int col = c0 + cl, h = col >> 6, n = col & 63;
    f16 tmp[16];
    #pragma unroll
    for (int j = 0; j < 16; ++j) tmp[j] = (f16)tile[kq*16 + j][cl];
    f16* dst = WC + (size_t)(h*128 + n)*256 + k0 + kq*16;
    *(f16x8*)dst       = *(f16x8*)&tmp[0];
    *(f16x8*)(dst + 8) = *(f16x8*)&tmp[8];
  } else if (b < 96) {
    const int bb = b - 32;
    const int h = bb >> 3, k0 = (bb & 7) * 32;
    const int k = t & 31, sq = t >> 5;
    float accs[8];
    #pragma unroll
    for (int j = 0; j < 8; ++j) accs[j] = 0.f;
    for (int d = 0; d < 64; ++d) {
      float a = Wx[(size_t)(k0 + k)*512 + h*64 + d];
      #pragma unroll
      for (int j = 0; j < 8; ++j) accs[j] += a * Wsl[d*64 + sq*8 + j];
    }
    #pragma unroll
    for (int j = 0; j < 8; ++j)
      WC[(size_t)(h*128 + 64 + sq*8 + j)*256 + k0 + k] = (f16)accs[j];
  } else if (b == 96) {
    for (int u = t; u < 512; u += 256) {
      int h = u >> 6, s = u & 63;
      float a = bsl[s];
      for (int d = 0; d < 64; ++d) a += bx[h*64 + d] * Wsl[d*64 + s];
      bsp[h*64 + s] = a;
    }
  } else {
    float4 z; z.x = z.y = z.z = z.w = 0.f;
    ((float4*)Tz)[(b - 97) * 256 + t] = z;
  }
}

// r4 body with the occupancy unlock:
// - OCCUPANCY LEDGER: r0 (256,2)+36K LDS -> 21% (=2 blocks, though LDS allowed
//   4); r5 (256,1) -> 11.5% (=1 block, though LDS allowed 2). Residency tracks
//   the 2nd launch_bounds arg, not LDS => hipcc maps it to waves-per-EU
//   (min,MAX) — it has been CAPPING co-residency all session. Fix: bare
//   __launch_bounds__(256) + amdgpu_waves_per_eu(4) (min-only: VGPR<=128, no
//   residency max).
// - LDS cut to 35840 B so 4 blocks/CU fit: single-buffered X staging (r0
//   layout) + W via global_load_lds single-buffer [128][64] with the
//   r5-VERIFIED both-sides XOR swizzle (source slot (l&7)^(l>>3), read addr
//   ^((ln&7)*8)). Removes per block: 256 W ds_writes + 256 W reg-loads +
//   16 VGPR (wr).
// - Counted vmcnt(8) at the mid-step barrier: the 8 xr prefetch loads (newer)
//   stay in flight; the 4 W-DMA (older, FIFO) are drained -> W landed.
// - Aliases: fxT = X region (kb3 X-reads drained by post-loop bar); wT = W
//   region (kb3 W-reads drained; next W-DMA issues after next leading bar,
//   which drains PhaseC's wT reads). Numerics/K-order identical to r4.
__global__ __launch_bounds__(256)
__attribute__((amdgpu_waves_per_eu(4)))
void fused_main(const float* __restrict__ x,   const float* __restrict__ bfx,
                const float* __restrict__ bsp, const float* __restrict__ temp,
                const f16* __restrict__ WC,    float* __restrict__ Tg,
                float* __restrict__ normg) {
  __shared__ alignas(1024) char smem[35840];
  f16* sm_x   = (f16*)smem;                // [128][72] X staging | alias fxT [64][136]
  f16* sm_fxT = sm_x;                      // 17408 <= 18432 ✓
  f16* sm_w   = (f16*)(smem + 18432);      // [128][64] W DMA     | alias wT  [64][136]
  f16* sm_wT  = sm_w;                      // region is 17408 B (16384 used by W tile)

  // XCD swizzle: all 8 heads of a chunk on one XCD
  const int j    = blockIdx.x;
  const int xcd  = j & 7, slot = j >> 3;
  const int chunk = xcd * 32 + (slot >> 3);
  const int h     = slot & 7;

  const int tid = threadIdx.x;
  const int wv = tid >> 6, lane = tid & 63, quad = lane >> 4, ln = lane & 15;
  const int wm = wv >> 1, wn = wv & 1;
  const long tokBase = (long)chunk * CHUNK;
  const int b  = (int)(tokBase >> 16);
  const int bh = b * Hc + h;

  const float tc = fminf(fmaxf(temp[h], 0.5f), 5.0f);
  const float k2 = 1.44269504f / tc;

  float bv[4];
  {
    const float* bb = (wn == 0) ? (bfx + h*64) : (bsp + h*64);
    #pragma unroll
    for (int nt = 0; nt < 4; ++nt) bv[nt] = bb[nt*16 + ln];
  }

  f32x4 Tacc[2][2];
  #pragma unroll
  for (int i = 0; i < 2; ++i) { Tacc[i][0] = splat4(0.f); Tacc[i][1] = splat4(0.f); }
  float nacc[4] = {0.f, 0.f, 0.f, 0.f};
  const int ci = wv >> 1, cj = wv & 1;

  const f16* WCh = WC + (size_t)h * 128 * 256;

  const int r0 = tid >> 2, seg = tid & 3;
  const int l8 = lane >> 3, sl = (lane & 7) ^ l8;   // DMA source slot (inverse swizzle)
  const int swl = (ln & 7) * 8;                     // W read swizzle (elems)

  float4 xr[8];
  auto loadx = [&](int m0, int kb) {
    const float* p = x + (tokBase + (long)m0*128 + r0)*Cc + kb*64 + seg*16;
    xr[0] = *(const float4*)p;        xr[1] = *(const float4*)(p + 4);
    xr[2] = *(const float4*)(p + 8);  xr[3] = *(const float4*)(p + 12);
    p += 64 * Cc;
    xr[4] = *(const float4*)p;        xr[5] = *(const float4*)(p + 4);
    xr[6] = *(const float4*)(p + 8);  xr[7] = *(const float4*)(p + 12);
  };
  // W panel tile [128 n][64 k] for k-block kb -> sm_w. 4 DMA instrs/wave,
  // wave wv covers rows wv*32..+31. Dest per instr is wave-uniform (m104).
  auto stageW = [&](int kb) {
    f16* dst = sm_w + wv * 2048;
    const f16* src = WCh + ((size_t)(wv*32 + l8))*256 + kb*64 + sl*8;
    #pragma unroll
    for (int i = 0; i < 4; ++i)
      gl_lds16(src + i*(8*256), dst + i*512);
  };

  loadx(0, 0);

  for (int m0 = 0; m0 < 4; ++m0) {
    // ---------- Phase A: [fx | sp] = x_tile(128x256) @ WC_h(256x128) ----------
    f32x4 acc[4][4];
    #pragma unroll
    for (int mt = 0; mt < 4; ++mt)
      #pragma unroll
      for (int nt = 0; nt < 4; ++nt) acc[mt][nt] = splat4(bv[nt]);

    for (int kb = 0; kb < 4; ++kb) {
      bar_lgkm();                          // prev frag/PhaseC reads drained (all waves)
      stageW(kb);                          // W(kb) DMA (overwrites prev W tile / wT)
      // X stores (compiler inserts the xr vmcnt wait; W-DMA is newer, stays)
      *(f16x8*)&sm_x[r0*LDX + seg*16]          = pack8(xr[0], xr[1]);
      *(f16x8*)&sm_x[r0*LDX + seg*16 + 8]      = pack8(xr[2], xr[3]);
      *(f16x8*)&sm_x[(r0+64)*LDX + seg*16]     = pack8(xr[4], xr[5]);
      *(f16x8*)&sm_x[(r0+64)*LDX + seg*16 + 8] = pack8(xr[6], xr[7]);
      { int nkb = kb + 1, nm0 = m0;
        if (nkb == 4) { nkb = 0; ++nm0; }
        if (nm0 < 4) loadx(nm0, nkb); }    // xr for next tile (8 newest VMEM)
      if (m0 == 3 && kb == 3) bar_vmN<0>(); else bar_vmN<8>();
      #pragma unroll
      for (int ks = 0; ks < 2; ++ks) {
        f16x8 af[4], bf[4];
        #pragma unroll
        for (int mt = 0; mt < 4; ++mt)
          af[mt] = *(const f16x8*)&sm_x[(wm*64 + mt*16 + ln)*LDX + ks*32 + quad*8];
        #pragma unroll
        for (int nt = 0; nt < 4; ++nt)
          bf[nt] = *(const f16x8*)&sm_w[(wn*64 + nt*16 + ln)*LDW + ((ks*32 + quad*8) ^ swl)];
        #pragma unroll
        for (int mt = 0; mt < 4; ++mt)
          #pragma unroll
          for (int nt = 0; nt < 4; ++nt)
            acc[mt][nt] = MFMA(af[mt], bf[nt], acc[mt][nt]);
      }
    }
    bar_lgkm();                            // kb3 X/W reads done -> alias rewrite ok

    // ---------- epilogue into aliased regions ----------
    if (wn == 0) {
      #pragma unroll
      for (int mt = 0; mt < 4; ++mt)
        #pragma unroll
        for (int nt = 0; nt < 4; ++nt) {
          f16x4 v = { (f16)acc[mt][nt][0], (f16)acc[mt][nt][1],
                      (f16)acc[mt][nt][2], (f16)acc[mt][nt][3] };
          *(f16x4*)&sm_fxT[(nt*16 + ln)*LDT + wm*64 + mt*16 + quad*4] = v;
        }
    } else {
      #pragma unroll
      for (int mt = 0; mt < 4; ++mt) {
        float e[4][4], wout[4][4];
        #pragma unroll
        for (int nt = 0; nt < 4; ++nt)
          #pragma unroll
          for (int rg = 0; rg < 4; ++rg)
            e[nt][rg] = exp2f(acc[mt][nt][rg] * k2);   // no max-sub: logits bounded
        #pragma unroll
        for (int rg = 0; rg < 4; ++rg) {
          float rs = e[0][rg] + e[1][rg] + e[2][rg] + e[3][rg];
          #pragma unroll
          for (int dd = 1; dd < 16; dd <<= 1) rs += __shfl_xor(rs, dd, 64);
          float inv = 1.0f / rs;
          #pragma unroll
          for (int nt = 0; nt < 4; ++nt) {
            wout[nt][rg] = e[nt][rg] * inv;
            nacc[nt] += wout[nt][rg];
          }
        }
        #pragma unroll
        for (int nt = 0; nt < 4; ++nt) {
          f16x4 v = { (f16)wout[nt][0], (f16)wout[nt][1],
                      (f16)wout[nt][2], (f16)wout[nt][3] };
          *(f16x4*)&sm_wT[(nt*16 + ln)*LDT + wm*64 + mt*16 + quad*4] = v;
        }
      }
    }
    bar_lgkm();                            // epilogue writes visible

    // ---------- Phase C: T[s][d] += w^T @ fx, K=128 ----------
    #pragma unroll
    for (int ks = 0; ks < 4; ++ks) {
      f16x8 a0 = *(const f16x8*)&sm_wT [(ci*32 +      ln)*LDT + ks*32 + quad*8];
      f16x8 a1 = *(const f16x8*)&sm_wT [(ci*32 + 16 + ln)*LDT + ks*32 + quad*8];
      f16x8 b0 = *(const f16x8*)&sm_fxT[(cj*32 +      ln)*LDT + ks*32 + quad*8];
      f16x8 b1 = *(const f16x8*)&sm_fxT[(cj*32 + 16 + ln)*LDT + ks*32 + quad*8];
      Tacc[0][0] = MFMA(a0, b0, Tacc[0][0]);
      Tacc[0][1] = MFMA(a0, b1, Tacc[0][1]);
      Tacc[1][0] = MFMA(a1, b0, Tacc[1][0]);
      Tacc[1][1] = MFMA(a1, b1, Tacc[1][1]);
    }
    // next m0's leading bar_lgkm drains these reads before the X-store /
    // W-DMA rewrite of the aliased regions.
  }

  // ---------- flush ----------
  float* Tb = Tg + bh * 4096;
  #pragma unroll
  for (int mt2 = 0; mt2 < 2; ++mt2)
    #pragma unroll
    for (int nt2 = 0; nt2 < 2; ++nt2)
      #pragma unroll
      for (int rg = 0; rg < 4; ++rg) {
        int s = ci*32 + mt2*16 + quad*4 + rg;
        int d = cj*32 + nt2*16 + ln;
        atomicAdd(&Tb[s*64 + d], Tacc[mt2][nt2][rg]);
      }
  if (wn == 1) {
    #pragma unroll
    for (int nt = 0; nt < 4; ++nt) {
      float v = nacc[nt];
      v += __shfl_xor(v, 16, 64);
      v += __shfl_xor(v, 32, 64);
      if (lane < 16) atomicAdd(&normg[bh*64 + nt*16 + ln], v);
    }
  }
}

__global__ void finalize(const float* __restrict__ Tg, const float* __restrict__ normg,
                         float* __restrict__ out) {
  int i = blockIdx.x * 256 + threadIdx.x;
  out[i] = Tg[i] / (normg[i >> 6] + 0.01f);
}

extern "C" void kernel_launch(void* const* d_in, const int* in_sizes, int n_in,
                              void* d_out, int out_size, void* d_ws, size_t ws_size,
                              hipStream_t stream) {
  const float* x    = (const float*)d_in[0];
  const float* Wx   = (const float*)d_in[1];
  const float* bx   = (const float*)d_in[2];
  const float* Wfx  = (const float*)d_in[3];
  const float* bfx  = (const float*)d_in[4];
  const float* Wsl  = (const float*)d_in[5];
  const float* bsl  = (const float*)d_in[6];
  const float* temp = (const float*)d_in[7];
  float* out = (float*)d_out;

  float* Tg    = (float*)d_ws;
  float* normg = Tg + 16 * 4096;
  f16*   WC    = (f16*)((char*)d_ws + 266240);
  float* bsp   = (float*)((char*)d_ws + 790528);

  prep_a    <<<162, 256, 0, stream>>>(Wx, Wfx, Wsl, bx, bsl, WC, bsp, Tg);
  fused_main<<<2048, 256, 0, stream>>>(x, bfx, bsp, temp, WC, Tg, normg);
  finalize  <<<256, 256, 0, stream>>>(Tg, normg, out);
}